// Round 6
// baseline (4276.942 us; speedup 1.0000x reference)
//
#include <hip/hip_runtime.h>

// VaeRNNDecoder: 512-step LSTM with output feedback, B=256, H=512.
// Folded recurrence: gates_t = h_t @ W_eff^T + b_eff,  W_eff = W_ih@W_last + W_hh.
// ROUND 6: 2-phase batch pipeline with COVERED latency. 8 groups x 16
// pair-blocks; group's 32 batches split A(0-15)/B(16-31); ticks alternate.
// Key fixes vs r5 (which cost a full exchange chain per tick):
//   - raw s_barrier + lgkmcnt(0) only (NO __syncthreads: it emits vmcnt(0)
//     and drains in-flight prefetch — r5's hidden killer).
//   - point A = COUNTED vmcnt (waits only the one-tick-old prefetch).
//   - point B = single vmcnt(0) (free: ops are ~1800cy old) -> per-WAVE
//     lane0 publish (vmcnt is a wave counter) -> all-wave spin on ONE line
//     -> prefetch issue covered by gates+bar+cell.
//   - h-store never drained explicitly; its ack gates next tick's publish.
// Ledger: r1/r2 sc0-only XCD exchange BROKEN (no release semantics). r3 wide
// polling floods LLC (poll ONE line). r4 barrier width is not a cost;
// broadcast BW and latency are. r5 prefetch adjacent to its wait = no overlap.

#define HH 512
#define TT 512

typedef _Float16 half8 __attribute__((ext_vector_type(8)));
typedef float f32x4 __attribute__((ext_vector_type(4)));

#define BAR()                                                  \
    do {                                                       \
        asm volatile("s_waitcnt lgkmcnt(0)" ::: "memory");     \
        __builtin_amdgcn_s_barrier();                          \
        asm volatile("" ::: "memory");                         \
    } while (0)

__device__ __forceinline__ float sigm(float x) { return 1.0f / (1.0f + __expf(-x)); }
__device__ __forceinline__ float tanh_(float x) { return 1.0f - 2.0f / (__expf(2.0f * x) + 1.0f); }
__device__ __forceinline__ unsigned short f16b(float x) {
    _Float16 h = (_Float16)x;
    return __builtin_bit_cast(unsigned short, h);
}

// ---------------- K1: W_eff gate rows -> Wbig (packed, f16) ----------------
__global__ __launch_bounds__(256) void k_weff(const float* __restrict__ Wih,
                                              const float* __restrict__ Whh,
                                              const float* __restrict__ Wlast,
                                              unsigned short* __restrict__ Wbig) {
    __shared__ float wih[16 * 512];
    const int tid = threadIdx.x;
    const int r0 = blockIdx.x * 16;
    for (int i = tid; i < (16 * 512) / 4; i += 256) {
        ((float4*)wih)[i] = ((const float4*)(Wih + (size_t)r0 * 512))[i];
    }
    __syncthreads();
    float acc0[16], acc1[16];
#pragma unroll
    for (int rr = 0; rr < 16; ++rr) { acc0[rr] = 0.f; acc1[rr] = 0.f; }
    const int k0 = tid * 2;
    for (int j = 0; j < 512; ++j) {
        const float2 wl = *(const float2*)(Wlast + (size_t)j * 512 + k0);
#pragma unroll
        for (int rr = 0; rr < 16; ++rr) {
            const float a = wih[rr * 512 + j];
            acc0[rr] += a * wl.x;
            acc1[rr] += a * wl.y;
        }
    }
#pragma unroll
    for (int rr = 0; rr < 16; ++rr) {
        const int gr = r0 + rr;
        const int q = gr >> 9, j = gr & 511;
        const int dst = 80 * (j >> 4) + q * 16 + (j & 15);
        const float v0 = acc0[rr] + Whh[(size_t)gr * 512 + k0];
        const float v1 = acc1[rr] + Whh[(size_t)gr * 512 + k0 + 1];
        Wbig[(size_t)dst * 512 + k0] = f16b(v0);
        Wbig[(size_t)dst * 512 + k0 + 1] = f16b(v1);
    }
}

// ---------------- K2: pack W0big, y-rows, biases, hbuf init, counters ------
__global__ __launch_bounds__(256) void k_pack(const float* __restrict__ z,
                                              const float* __restrict__ Wih,
                                              const float* __restrict__ Whh,
                                              const float* __restrict__ bih,
                                              const float* __restrict__ bhh,
                                              const float* __restrict__ Wlast,
                                              const float* __restrict__ blast,
                                              unsigned short* __restrict__ Wbig,
                                              unsigned short* __restrict__ W0big,
                                              float* __restrict__ biasEff,
                                              float* __restrict__ bias0,
                                              unsigned short* __restrict__ hbuf,
                                              unsigned int* __restrict__ counters) {
    const int nthr = gridDim.x * blockDim.x;
    const int gtid = blockIdx.x * blockDim.x + threadIdx.x;
    for (int e = gtid; e < 2560 * 512; e += nthr) {
        const int r = e >> 9, k = e & 511;
        const int s = r / 80, rem = r - s * 80;
        const int tau = rem >> 4, jj = rem & 15;
        const int j = s * 16 + jj;
        if (tau == 4) {
            const unsigned short v = f16b(Wlast[(size_t)j * 512 + k]);
            Wbig[e] = v;
            W0big[e] = v;
        } else {
            const int gr = tau * 512 + j;
            W0big[e] = f16b(Wih[(size_t)gr * 512 + k] + Whh[(size_t)gr * 512 + k]);
        }
    }
    for (int r = gtid; r < 2560; r += nthr) {
        const int s = r / 80, rem = r - s * 80;
        const int tau = rem >> 4, jj = rem & 15;
        const int j = s * 16 + jj;
        if (tau == 4) {
            bias0[r] = blast[j];
            biasEff[r] = blast[j];
        } else {
            const int gr = tau * 512 + j;
            const float base = bih[gr] + bhh[gr];
            float dot = 0.f;
            for (int k = 0; k < 512; ++k) dot += Wih[(size_t)gr * 512 + k] * blast[k];
            bias0[r] = base;
            biasEff[r] = base + dot;
        }
    }
    // hbuf layout: [g][buf 0..3][16 batch][512], buf = half*2 + parity.
    for (int e = gtid; e < 256 * 512; e += nthr) {
        const int bg = e >> 9, k = e & 511;
        const int g = bg >> 5, bl = bg & 31;
        const int hf = bl >> 4, b16 = bl & 15;
        hbuf[(size_t)g * 32768 + (size_t)(hf * 2) * 8192 + b16 * 512 + k] = f16b(z[e]);
    }
    for (int e = gtid; e < 512; e += nthr) counters[e] = 0u;
}

// ---------------- K3: persistent recurrence, pipelined 2-phase ----------------
// 128 blocks = 8 groups (blockIdx&7) x 16 pairs (blockIdx>>3). 1026 ticks:
// tick T -> half=T&1, k=T>>1. Waves: w0 slA{i,f,g}, w1 slA{o,y}, w2 slB{i,f,g},
// w3 slB{o,y}. Per-thread vmem order per steady tick (vmcnt bookkeeping):
//   prefetch(4 asm loads) ... y(4 C++ stores, w1/3) ... h(1 asm sc0sc1 store)
// point A waits vmcnt(5)/(1) -> exactly the prefetch retired, stores ride on.
__global__ __launch_bounds__(256, 1) void k_lstm(const unsigned short* __restrict__ Wbig,
                                                 const unsigned short* __restrict__ W0big,
                                                 const float* __restrict__ biasEff,
                                                 const float* __restrict__ bias0,
                                                 unsigned short* __restrict__ hbuf,
                                                 unsigned int* __restrict__ counters,
                                                 const float* __restrict__ z,
                                                 float* __restrict__ out) {
    const int g = blockIdx.x & 7;
    const int pair = blockIdx.x >> 3;
    const int tid = threadIdx.x;
    const int wave = tid >> 6;
    const int lane = tid & 63;
    const int l15 = lane & 15;
    const int q4 = lane >> 4;

    __shared__ unsigned short hstage[16 * 520];  // one half's h, padded rows
    __shared__ float gatesL[2 * 16 * 68];        // [sl][b][i f g o], stride 68
    __shared__ float cL[4 * 16 * 18];            // [half*2+sl][b][16], stride 18

    const int sl = wave >> 1;
    const int slice = 2 * pair + sl;
    const int ntile0 = (wave & 1) ? 3 : 0;
    const int ntcount = (wave & 1) ? 2 : 3;

    unsigned short* hbg = hbuf + (size_t)g * 32768;
    unsigned int* cntA = counters + g * 64;       // half A generation counter
    unsigned int* cntB = counters + g * 64 + 16;  // half B generation counter

    // c init from z (fp32 exact): both halves x both slices
    for (int idx = tid; idx < 1024; idx += 256) {
        const int jj = idx & 15, b = (idx >> 4) & 15;
        const int s2 = (idx >> 8) & 1, hf = idx >> 9;
        cL[((hf * 2 + s2) * 16 + b) * 18 + jj] =
            z[(size_t)(g * 32 + hf * 16 + b) * 512 + 16 * (2 * pair + s2) + jj];
    }

    // persistent B-fragments (fp16 weights), start with W0
    half8 bfrag[3][16];
#pragma unroll
    for (int tt = 0; tt < 3; ++tt) {
        if (tt < ntcount) {
            const int row = 80 * slice + (ntile0 + tt) * 16 + l15;
#pragma unroll
            for (int kk = 0; kk < 16; ++kk) {
                bfrag[tt][kk] = *(const half8*)(W0big + (size_t)row * 512 + kk * 32 + q4 * 8);
            }
        }
    }
    float bias0v[3], biasEv[3];
#pragma unroll
    for (int tt = 0; tt < 3; ++tt) {
        if (tt < ntcount) {
            const int r = 80 * slice + (ntile0 + tt) * 16 + l15;
            bias0v[tt] = bias0[r];
            biasEv[tt] = biasEff[r];
        } else {
            bias0v[tt] = 0.f;
            biasEv[tt] = 0.f;
        }
    }

    __syncthreads();  // cL init visible (pre-loop: implicit drain harmless)

    // prologue: prefetch hA(0) (buffer 0, seeded by k_pack), no wait
    half8 st[4];
    {
        const char* p = (const char*)hbg + tid * 16;
        asm volatile(
            "global_load_dwordx4 %0, %4, off sc0 sc1\n\t"
            "global_load_dwordx4 %1, %5, off sc0 sc1\n\t"
            "global_load_dwordx4 %2, %6, off sc0 sc1\n\t"
            "global_load_dwordx4 %3, %7, off sc0 sc1"
            : "=&v"(st[0]), "=&v"(st[1]), "=&v"(st[2]), "=&v"(st[3])
            : "v"(p), "v"(p + 4096), "v"(p + 8192), "v"(p + 12288)
            : "memory");
    }

    for (int tick = 0; tick < 1026; ++tick) {
        const int k = tick >> 1;
        const int half = tick & 1;
        const bool last = (k == 512);

        // ---- point A: counted wait -> only the one-tick-old prefetch ----
        if (tick <= 2 || tick == 1025) {
            asm volatile("s_waitcnt vmcnt(0)" ::: "memory");
        } else if (wave & 1) {
            asm volatile("s_waitcnt vmcnt(5)" ::: "memory");
        } else {
            asm volatile("s_waitcnt vmcnt(1)" ::: "memory");
        }
        __builtin_amdgcn_sched_barrier(0);
#pragma unroll
        for (int i = 0; i < 4; ++i) {
            const int ci = i * 256 + tid;  // 16B chunk: 16 rows x 64 chunks
            const int row = ci >> 6, col = ci & 63;
            *(half8*)(hstage + row * 520 + col * 8) = st[i];
        }
        BAR();

        // ---- MFMA: one 16-batch M-tile x [gates | y] ----
        f32x4 acc[3];
#pragma unroll
        for (int tt = 0; tt < 3; ++tt) {
            const float bv = (k == 0) ? bias0v[tt] : biasEv[tt];
            acc[tt] = (f32x4){bv, bv, bv, bv};
        }
#pragma unroll
        for (int kk = 0; kk < 16; ++kk) {
            const half8 a = *(const half8*)(hstage + l15 * 520 + kk * 32 + q4 * 8);
#pragma unroll
            for (int tt = 0; tt < 3; ++tt) {
                if (tt < ntcount)
                    acc[tt] = __builtin_amdgcn_mfma_f32_16x16x32_f16(a, bfrag[tt][kk], acc[tt], 0, 0, 0);
            }
        }

        // ---- point B: release prev tick's h stores (ack is ~1800cy old) ----
        asm volatile("s_waitcnt vmcnt(0)" ::: "memory");
        // publish h stored at tick-1 (half (tick-1)&1): per-wave lane0; vmcnt
        // is a WAVE counter, so each wave's ack covers all its lanes' stores.
        if (tick >= 1 && tick <= 1024 && lane == 0) {
            unsigned int* cp = (tick & 1) ? cntA : cntB;  // (tick-1)&1
            __hip_atomic_fetch_add(cp, 1u, __ATOMIC_RELAXED, __HIP_MEMORY_SCOPE_AGENT);
        }
        if (tick < 1025) {
            const int knext = (tick + 1) >> 1;
            unsigned int* cy = ((tick + 1) & 1) ? cntB : cntA;
            if (knext > 0) {
                // self-syncing spin: ONE line per group, all lanes same addr
                const unsigned int tgt = 64u * (unsigned)knext;
                unsigned int pv;
                int gd = 0;
                do {
                    asm volatile("global_load_dword %0, %1, off sc0 sc1\n\ts_waitcnt vmcnt(0)"
                                 : "=v"(pv)
                                 : "v"(cy)
                                 : "memory");
                } while (pv < tgt && ++gd < 65536);
            }
            // prefetch next tick's h; latency covered by gates+bar+y+cell
            const char* p =
                (const char*)(hbg + (((tick + 1) & 1) * 2 + (knext & 1)) * 8192) + tid * 16;
            asm volatile(
                "global_load_dwordx4 %0, %4, off sc0 sc1\n\t"
                "global_load_dwordx4 %1, %5, off sc0 sc1\n\t"
                "global_load_dwordx4 %2, %6, off sc0 sc1\n\t"
                "global_load_dwordx4 %3, %7, off sc0 sc1"
                : "=&v"(st[0]), "=&v"(st[1]), "=&v"(st[2]), "=&v"(st[3])
                : "v"(p), "v"(p + 4096), "v"(p + 8192), "v"(p + 12288)
                : "memory");
        }
        // one-time W0 -> W_eff swap after both halves' step 0; vmcnt(0)
        // restores clean counting (drains swap loads + this tick's prefetch)
        if (tick == 1) {
#pragma unroll
            for (int tt = 0; tt < 3; ++tt) {
                if (tt < ntcount) {
                    const int row = 80 * slice + (ntile0 + tt) * 16 + l15;
#pragma unroll
                    for (int kk = 0; kk < 16; ++kk) {
                        bfrag[tt][kk] = *(const half8*)(Wbig + (size_t)row * 512 + kk * 32 + q4 * 8);
                    }
                }
            }
            asm volatile("s_waitcnt vmcnt(0)" ::: "memory");
        }

        // ---- gate tiles -> LDS ----
        if (!last) {
            const int nst = (wave & 1) ? 1 : 3;
#pragma unroll
            for (int tt = 0; tt < 3; ++tt) {
                if (tt < nst) {
                    const int col = (ntile0 + tt) * 16 + l15;
#pragma unroll
                    for (int r = 0; r < 4; ++r) {
                        const int m = q4 * 4 + r;
                        gatesL[(sl * 16 + m) * 68 + col] = acc[tt][r];
                    }
                }
            }
        }
        BAR();

        // ---- y_{k-1} output (waves 1/3, acc[1]); plain stores, count=4 ----
        if ((wave & 1) && k >= 1) {
            const int n = 16 * slice + l15;
#pragma unroll
            for (int r = 0; r < 4; ++r) {
                const int m = q4 * 4 + r;
                const size_t off =
                    (size_t)(g * 32 + half * 16 + m) * (TT * HH) + (size_t)(k - 1) * HH + n;
                out[off] = acc[1][r];
            }
        }

        if (!last) {
            // ---- cell update: 2 cells/thread; h-store (NO drain here) ----
            const int b = tid >> 4, jp = tid & 15;
            const int j0 = jp * 2;
            const int s2 = j0 >> 4, jj = j0 & 15;
            const float* gb = gatesL + (s2 * 16 + b) * 68;
            const float2 iv = *(const float2*)(gb + jj);
            const float2 fvv = *(const float2*)(gb + 16 + jj);
            const float2 gv = *(const float2*)(gb + 32 + jj);
            const float2 ov = *(const float2*)(gb + 48 + jj);
            float* cp = cL + ((half * 2 + s2) * 16 + b) * 18 + jj;
            float2 cv = *(const float2*)cp;
            const float c0 = sigm(fvv.x) * cv.x + sigm(iv.x) * tanh_(gv.x);
            const float c1 = sigm(fvv.y) * cv.y + sigm(iv.y) * tanh_(gv.y);
            const float h0 = sigm(ov.x) * tanh_(c0);
            const float h1 = sigm(ov.y) * tanh_(c1);
            cv.x = c0;
            cv.y = c1;
            *(float2*)cp = cv;
            unsigned short* hd = hbg + (half * 2 + ((k + 1) & 1)) * 8192;
            const unsigned int packed = (unsigned int)f16b(h0) | ((unsigned int)f16b(h1) << 16);
            unsigned int* pp = (unsigned int*)(hd + b * 512 + 16 * (2 * pair + s2) + jj);
            asm volatile("global_store_dword %0, %1, off sc0 sc1" ::"v"(pp), "v"(packed)
                         : "memory");
        }
    }
}

// ---------------- launch ----------------
extern "C" void kernel_launch(void* const* d_in, const int* in_sizes, int n_in,
                              void* d_out, int out_size, void* d_ws, size_t ws_size,
                              hipStream_t stream) {
    const float* z = (const float*)d_in[0];
    const float* Wih = (const float*)d_in[1];
    const float* Whh = (const float*)d_in[2];
    const float* bih = (const float*)d_in[3];
    const float* bhh = (const float*)d_in[4];
    const float* Wlast = (const float*)d_in[5];
    const float* blast = (const float*)d_in[6];
    float* out = (float*)d_out;

    char* ws = (char*)d_ws;
    unsigned short* Wbig = (unsigned short*)(ws);                // 2,621,440 B
    unsigned short* W0big = (unsigned short*)(ws + 2621440);     // 2,621,440 B
    float* biasEff = (float*)(ws + 5242880);                     // 10,240 B
    float* bias0 = (float*)(ws + 5253120);                       // 10,240 B
    unsigned short* hbuf = (unsigned short*)(ws + 5263360);      // 524,288 B
    unsigned int* counters = (unsigned int*)(ws + 5787648);      // 2,048 B

    k_weff<<<128, 256, 0, stream>>>(Wih, Whh, Wlast, Wbig);
    k_pack<<<512, 256, 0, stream>>>(z, Wih, Whh, bih, bhh, Wlast, blast, Wbig, W0big, biasEff,
                                    bias0, hbuf, counters);
    k_lstm<<<128, 256, 0, stream>>>(Wbig, W0big, biasEff, bias0, hbuf, counters, z, out);
}

// Round 7
// 3393.106 us; speedup vs baseline: 1.2605x; 1.2605x over previous
//
#include <hip/hip_runtime.h>

// VaeRNNDecoder: 512-step LSTM with output feedback, B=256, H=512.
// Folded recurrence: gates_t = h_t @ W_eff^T + b_eff,  W_eff = W_ih@W_last + W_hh.
// ROUND 7: r4 structure (8 groups x 16 pair-blocks, 160 rows/block, one
// rendezvous per step, 4 MB/step broadcast) with a cheaper rendezvous:
//   - per-WAVE release: wave drains its own h-stores (vmcnt is a wave
//     counter), lane0 plain-stores flag=t+1 to its own dword (64 flags =
//     256B/group). No fetch_add RMW chain, no pre-publish __syncthreads.
//   - wave0 detects via ONE lane-indexed coalesced load (4 lines/group) +
//     __ballot; raw s_barrier wake (no vmcnt drain).
//   - y-stores issued AFTER the flag; they drain for free next stage.
// Ledger: r1/r2 sc0-only XCD exchange BROKEN (no release). r3 wide polling
// floods LLC (keep polls narrow). r4 broadcast BW+latency dominate, RMW width
// secondary. r5/r6 2-phase tick pipeline doubles rendezvous count and loses
// ~2x; per-wave fetch_add on one line (64 RMWs) catastrophically serializes.

#define HH 512
#define TT 512

typedef _Float16 half8 __attribute__((ext_vector_type(8)));
typedef float f32x4 __attribute__((ext_vector_type(4)));

#define BAR()                                              \
    do {                                                   \
        asm volatile("s_waitcnt lgkmcnt(0)" ::: "memory"); \
        __builtin_amdgcn_s_barrier();                      \
        asm volatile("" ::: "memory");                     \
    } while (0)

__device__ __forceinline__ float sigm(float x) { return 1.0f / (1.0f + __expf(-x)); }
__device__ __forceinline__ float tanh_(float x) { return 1.0f - 2.0f / (__expf(2.0f * x) + 1.0f); }
__device__ __forceinline__ unsigned short f16b(float x) {
    _Float16 h = (_Float16)x;
    return __builtin_bit_cast(unsigned short, h);
}

// ---------------- K1: W_eff gate rows -> Wbig (packed, f16) ----------------
__global__ __launch_bounds__(256) void k_weff(const float* __restrict__ Wih,
                                              const float* __restrict__ Whh,
                                              const float* __restrict__ Wlast,
                                              unsigned short* __restrict__ Wbig) {
    __shared__ float wih[16 * 512];
    const int tid = threadIdx.x;
    const int r0 = blockIdx.x * 16;
    for (int i = tid; i < (16 * 512) / 4; i += 256) {
        ((float4*)wih)[i] = ((const float4*)(Wih + (size_t)r0 * 512))[i];
    }
    __syncthreads();
    float acc0[16], acc1[16];
#pragma unroll
    for (int rr = 0; rr < 16; ++rr) { acc0[rr] = 0.f; acc1[rr] = 0.f; }
    const int k0 = tid * 2;
    for (int j = 0; j < 512; ++j) {
        const float2 wl = *(const float2*)(Wlast + (size_t)j * 512 + k0);
#pragma unroll
        for (int rr = 0; rr < 16; ++rr) {
            const float a = wih[rr * 512 + j];
            acc0[rr] += a * wl.x;
            acc1[rr] += a * wl.y;
        }
    }
#pragma unroll
    for (int rr = 0; rr < 16; ++rr) {
        const int gr = r0 + rr;
        const int q = gr >> 9, j = gr & 511;
        const int dst = 80 * (j >> 4) + q * 16 + (j & 15);
        const float v0 = acc0[rr] + Whh[(size_t)gr * 512 + k0];
        const float v1 = acc1[rr] + Whh[(size_t)gr * 512 + k0 + 1];
        Wbig[(size_t)dst * 512 + k0] = f16b(v0);
        Wbig[(size_t)dst * 512 + k0 + 1] = f16b(v1);
    }
}

// ---------------- K2: pack W0big, y-rows, biases, hbuf init, flags ------
__global__ __launch_bounds__(256) void k_pack(const float* __restrict__ z,
                                              const float* __restrict__ Wih,
                                              const float* __restrict__ Whh,
                                              const float* __restrict__ bih,
                                              const float* __restrict__ bhh,
                                              const float* __restrict__ Wlast,
                                              const float* __restrict__ blast,
                                              unsigned short* __restrict__ Wbig,
                                              unsigned short* __restrict__ W0big,
                                              float* __restrict__ biasEff,
                                              float* __restrict__ bias0,
                                              unsigned short* __restrict__ hbuf,
                                              unsigned int* __restrict__ flags) {
    const int nthr = gridDim.x * blockDim.x;
    const int gtid = blockIdx.x * blockDim.x + threadIdx.x;
    for (int e = gtid; e < 2560 * 512; e += nthr) {
        const int r = e >> 9, k = e & 511;
        const int s = r / 80, rem = r - s * 80;
        const int tau = rem >> 4, jj = rem & 15;
        const int j = s * 16 + jj;
        if (tau == 4) {
            const unsigned short v = f16b(Wlast[(size_t)j * 512 + k]);
            Wbig[e] = v;
            W0big[e] = v;
        } else {
            const int gr = tau * 512 + j;
            W0big[e] = f16b(Wih[(size_t)gr * 512 + k] + Whh[(size_t)gr * 512 + k]);
        }
    }
    for (int r = gtid; r < 2560; r += nthr) {
        const int s = r / 80, rem = r - s * 80;
        const int tau = rem >> 4, jj = rem & 15;
        const int j = s * 16 + jj;
        if (tau == 4) {
            bias0[r] = blast[j];
            biasEff[r] = blast[j];
        } else {
            const int gr = tau * 512 + j;
            const float base = bih[gr] + bhh[gr];
            float dot = 0.f;
            for (int k = 0; k < 512; ++k) dot += Wih[(size_t)gr * 512 + k] * blast[k];
            bias0[r] = base;
            biasEff[r] = base + dot;
        }
    }
    // hbuf: [g][parity][32 batch][512]; seed parity 0 with z
    for (int e = gtid; e < 256 * 512; e += nthr) {
        const int b = e >> 9, k = e & 511;
        const int g = b >> 5, bl = b & 31;
        hbuf[((size_t)(g * 2) * 32 + bl) * 512 + k] = f16b(z[e]);
    }
    // flags: 8 groups x 64 wave-slots (4B each, 256B/group)
    for (int e = gtid; e < 512; e += nthr) flags[e] = 0u;
}

// ---------------- K3: persistent recurrence ----------------
// 128 blocks = 8 groups (blockIdx&7) x 16 pairs (blockIdx>>3). Pair-block
// owns slices {2p,2p+1} = 160 packed rows (128 gate rows + 32 y rows).
// Waves: w0: sliceA x {i,f,g}; w1: sliceA x {o,y}; w2: sliceB x {i,f,g};
//        w3: sliceB x {o,y}; each wave covers both 16-batch M-tiles.
__global__ __launch_bounds__(256, 1) void k_lstm(const unsigned short* __restrict__ Wbig,
                                                 const unsigned short* __restrict__ W0big,
                                                 const float* __restrict__ biasEff,
                                                 const float* __restrict__ bias0,
                                                 unsigned short* __restrict__ hbuf,
                                                 unsigned int* __restrict__ flags,
                                                 const float* __restrict__ z,
                                                 float* __restrict__ out) {
    const int g = blockIdx.x & 7;
    const int pair = blockIdx.x >> 3;
    const int tid = threadIdx.x;
    const int wave = tid >> 6;
    const int lane = tid & 63;
    const int l15 = lane & 15;
    const int q4 = lane >> 4;

    __shared__ unsigned short hstage[32 * 520];  // padded rows: stride 520 halves
    __shared__ float gatesL[2 * 32 * 68];        // [sl][b][i f g o], stride 68
    __shared__ float cL[2 * 32 * 18];            // [sl][b][16 cells], stride 18

    const int sl = wave >> 1;
    const int slice = 2 * pair + sl;
    const int ntile0 = (wave & 1) ? 3 : 0;
    const int ntcount = (wave & 1) ? 2 : 3;

    unsigned short* hb0 = hbuf + (size_t)(g * 2) * 32 * 512;
    unsigned short* hb1 = hb0 + 32 * 512;
    unsigned int* fgrp = flags + g * 64;  // this group's 64 wave flags

    // c init from z (fp32 exact) — both slices of the pair
    for (int idx = tid; idx < 1024; idx += 256) {
        const int s2 = idx >> 9;
        const int b = (idx >> 4) & 31, jj = idx & 15;
        cL[(s2 * 32 + b) * 18 + jj] =
            z[(size_t)(g * 32 + b) * 512 + 16 * (2 * pair + s2) + jj];
    }

    // persistent B-fragments (fp16 weights), start with W0
    half8 bfrag[3][16];
#pragma unroll
    for (int tt = 0; tt < 3; ++tt) {
        if (tt < ntcount) {
            const int row = 80 * slice + (ntile0 + tt) * 16 + l15;
#pragma unroll
            for (int kk = 0; kk < 16; ++kk) {
                bfrag[tt][kk] = *(const half8*)(W0big + (size_t)row * 512 + kk * 32 + q4 * 8);
            }
        }
    }
    float bias0v[3], biasEv[3];
#pragma unroll
    for (int tt = 0; tt < 3; ++tt) {
        if (tt < ntcount) {
            const int r = 80 * slice + (ntile0 + tt) * 16 + l15;
            bias0v[tt] = bias0[r];
            biasEv[tt] = biasEff[r];
        } else {
            bias0v[tt] = 0.f;
            biasEv[tt] = 0.f;
        }
    }

    __syncthreads();  // cL init visible (pre-loop, implicit drain harmless)

    for (int t = 0; t <= 512; ++t) {
        // ---- stage h(t): coherent LLC loads (sc0 sc1), one wait ----
        // vmcnt(0) also drains the previous step's y-stores (issued ~1500cy
        // ago -> free). Outputs MUST be early-clobber (=&v).
        {
            const unsigned short* src = (t & 1) ? hb1 : hb0;
            const char* p = (const char*)src + tid * 16;
            half8 st[8];
            asm volatile(
                "global_load_dwordx4 %0, %8, off sc0 sc1\n\t"
                "global_load_dwordx4 %1, %9, off sc0 sc1\n\t"
                "global_load_dwordx4 %2, %10, off sc0 sc1\n\t"
                "global_load_dwordx4 %3, %11, off sc0 sc1\n\t"
                "global_load_dwordx4 %4, %12, off sc0 sc1\n\t"
                "global_load_dwordx4 %5, %13, off sc0 sc1\n\t"
                "global_load_dwordx4 %6, %14, off sc0 sc1\n\t"
                "global_load_dwordx4 %7, %15, off sc0 sc1\n\t"
                "s_waitcnt vmcnt(0)"
                : "=&v"(st[0]), "=&v"(st[1]), "=&v"(st[2]), "=&v"(st[3]),
                  "=&v"(st[4]), "=&v"(st[5]), "=&v"(st[6]), "=&v"(st[7])
                : "v"(p), "v"(p + 4096), "v"(p + 8192), "v"(p + 12288),
                  "v"(p + 16384), "v"(p + 20480), "v"(p + 24576), "v"(p + 28672)
                : "memory");
#pragma unroll
            for (int i = 0; i < 8; ++i) {
                const int ci = i * 256 + tid;  // 16B chunk index, 0..2047
                const int row = ci >> 6, col = ci & 63;
                *(half8*)(hstage + row * 520 + col * 8) = st[i];
            }
        }
        BAR();

        // ---- MFMA: [gates | y] = h @ Wbig_pair^T + bias, both M-tiles ----
        f32x4 acc[3][2];
#pragma unroll
        for (int tt = 0; tt < 3; ++tt) {
            const float bv = (t == 0) ? bias0v[tt] : biasEv[tt];
            acc[tt][0] = (f32x4){bv, bv, bv, bv};
            acc[tt][1] = (f32x4){bv, bv, bv, bv};
        }
#pragma unroll
        for (int kk = 0; kk < 16; ++kk) {
            const half8 a0 = *(const half8*)(hstage + (l15)*520 + kk * 32 + q4 * 8);
            const half8 a1 = *(const half8*)(hstage + (16 + l15) * 520 + kk * 32 + q4 * 8);
#pragma unroll
            for (int tt = 0; tt < 3; ++tt) {
                if (tt < ntcount) {
                    acc[tt][0] = __builtin_amdgcn_mfma_f32_16x16x32_f16(a0, bfrag[tt][kk], acc[tt][0], 0, 0, 0);
                    acc[tt][1] = __builtin_amdgcn_mfma_f32_16x16x32_f16(a1, bfrag[tt][kk], acc[tt][1], 0, 0, 0);
                }
            }
        }

        if (t == 512) {
            // final y only, then done (kernel end drains stores)
            if (wave & 1) {
                const int n = 16 * slice + l15;
#pragma unroll
                for (int mt = 0; mt < 2; ++mt) {
#pragma unroll
                    for (int r = 0; r < 4; ++r) {
                        const int m = mt * 16 + q4 * 4 + r;
                        const size_t off =
                            (size_t)(g * 32 + m) * (TT * HH) + (size_t)(t - 1) * HH + n;
                        out[off] = acc[1][mt][r];
                    }
                }
            }
            break;
        }

        // ---- gate tiles -> LDS ----
        {
            const int nst = (wave & 1) ? 1 : 3;
#pragma unroll
            for (int tt = 0; tt < 3; ++tt) {
                if (tt < nst) {
                    const int col = (ntile0 + tt) * 16 + l15;
#pragma unroll
                    for (int mt = 0; mt < 2; ++mt) {
#pragma unroll
                        for (int r = 0; r < 4; ++r) {
                            const int m = mt * 16 + q4 * 4 + r;
                            gatesL[(sl * 32 + m) * 68 + col] = acc[tt][mt][r];
                        }
                    }
                }
            }
        }
        BAR();

        // ---- cell update: 4 cells/thread (2 slices x 2); h-stores ASAP ----
        {
            const int b = tid >> 3, jp = tid & 7;
            const int j0 = jp * 2;
            unsigned short* dst = (t & 1) ? hb0 : hb1;  // parity (t+1)&1
#pragma unroll
            for (int s2 = 0; s2 < 2; ++s2) {
                const float* gb = gatesL + (s2 * 32 + b) * 68;
                const float2 iv = *(const float2*)(gb + j0);
                const float2 fvv = *(const float2*)(gb + 16 + j0);
                const float2 gv = *(const float2*)(gb + 32 + j0);
                const float2 ov = *(const float2*)(gb + 48 + j0);
                float2 cv = *(const float2*)(cL + (s2 * 32 + b) * 18 + j0);
                const float c0 = sigm(fvv.x) * cv.x + sigm(iv.x) * tanh_(gv.x);
                const float c1 = sigm(fvv.y) * cv.y + sigm(iv.y) * tanh_(gv.y);
                const float h0 = sigm(ov.x) * tanh_(c0);
                const float h1 = sigm(ov.y) * tanh_(c1);
                cv.x = c0;
                cv.y = c1;
                *(float2*)(cL + (s2 * 32 + b) * 18 + j0) = cv;
                const unsigned int packed =
                    (unsigned int)f16b(h0) | ((unsigned int)f16b(h1) << 16);
                unsigned int* pp = (unsigned int*)(dst + b * 512 + 16 * (2 * pair + s2) + j0);
                asm volatile("global_store_dword %0, %1, off sc0 sc1" ::"v"(pp), "v"(packed)
                             : "memory");
            }
        }

        // after step 0, swap persistent weights W0 -> W_eff (loads drained by
        // the release vmcnt(0) below)
        if (t == 0) {
#pragma unroll
            for (int tt = 0; tt < 3; ++tt) {
                if (tt < ntcount) {
                    const int row = 80 * slice + (ntile0 + tt) * 16 + l15;
#pragma unroll
                    for (int kk = 0; kk < 16; ++kk) {
                        bfrag[tt][kk] = *(const half8*)(Wbig + (size_t)row * 512 + kk * 32 + q4 * 8);
                    }
                }
            }
        }

        // ---- per-WAVE release: drain own h-stores, lane0 flag store ----
        // vmcnt is a wave counter: vmcnt(0) acks ALL this wave's lanes' h
        // stores at the LLC -> the flag store (same wave, after the wait) is
        // ordered behind them. Consumers need all 64 flags, covering every
        // lane's stores. No RMW, no block-wide barrier before publish.
        asm volatile("s_waitcnt vmcnt(0)" ::: "memory");
        if (lane == 0) {
            unsigned int* fp = fgrp + pair * 4 + wave;
            const unsigned int fv = (unsigned int)t + 1u;
            asm volatile("global_store_dword %0, %1, off sc0 sc1" ::"v"(fp), "v"(fv)
                         : "memory");
        }

        // ---- y_{t-1} (waves 1/3): issued AFTER the flag; drains next stage ----
        if ((wave & 1) && t >= 1) {
            const int n = 16 * slice + l15;
#pragma unroll
            for (int mt = 0; mt < 2; ++mt) {
#pragma unroll
                for (int r = 0; r < 4; ++r) {
                    const int m = mt * 16 + q4 * 4 + r;
                    const size_t off =
                        (size_t)(g * 32 + m) * (TT * HH) + (size_t)(t - 1) * HH + n;
                    out[off] = acc[1][mt][r];
                }
            }
        }

        // ---- detect: wave0 polls 64 flags with ONE coalesced load ----
        // (4 LLC lines/group/iter — narrow; r3's flood was 100x wider.)
        if (wave == 0) {
            const unsigned int* fp = fgrp + lane;
            const unsigned int tgt = (unsigned int)t + 1u;
            unsigned int pv;
            int gd = 0;
            do {
                asm volatile("global_load_dword %0, %1, off sc0 sc1\n\ts_waitcnt vmcnt(0)"
                             : "=v"(pv)
                             : "v"(fp)
                             : "memory");
            } while (__ballot(pv >= tgt) != ~0ull && ++gd < 65536);
        }
        BAR();  // raw wake: no vmcnt drain (y-stores ride across)
    }
}

// ---------------- launch ----------------
extern "C" void kernel_launch(void* const* d_in, const int* in_sizes, int n_in,
                              void* d_out, int out_size, void* d_ws, size_t ws_size,
                              hipStream_t stream) {
    const float* z = (const float*)d_in[0];
    const float* Wih = (const float*)d_in[1];
    const float* Whh = (const float*)d_in[2];
    const float* bih = (const float*)d_in[3];
    const float* bhh = (const float*)d_in[4];
    const float* Wlast = (const float*)d_in[5];
    const float* blast = (const float*)d_in[6];
    float* out = (float*)d_out;

    char* ws = (char*)d_ws;
    unsigned short* Wbig = (unsigned short*)(ws);                // 2,621,440 B
    unsigned short* W0big = (unsigned short*)(ws + 2621440);     // 2,621,440 B
    float* biasEff = (float*)(ws + 5242880);                     // 10,240 B
    float* bias0 = (float*)(ws + 5253120);                       // 10,240 B
    unsigned short* hbuf = (unsigned short*)(ws + 5263360);      // 524,288 B
    unsigned int* flags = (unsigned int*)(ws + 5787648);         // 2,048 B

    k_weff<<<128, 256, 0, stream>>>(Wih, Whh, Wlast, Wbig);
    k_pack<<<512, 256, 0, stream>>>(z, Wih, Whh, bih, bhh, Wlast, blast, Wbig, W0big, biasEff,
                                    bias0, hbuf, flags);
    k_lstm<<<128, 256, 0, stream>>>(Wbig, W0big, biasEff, bias0, hbuf, flags, z, out);
}

// Round 8
// 2203.541 us; speedup vs baseline: 1.9409x; 1.5398x over previous
//
#include <hip/hip_runtime.h>

// VaeRNNDecoder: 512-step LSTM with output feedback, B=256, H=512.
// Folded recurrence: gates_t = h_t @ W_eff^T + b_eff,  W_eff = W_ih@W_last + W_hh.
// ROUND 8: r4 structure VERBATIM (8 groups x 16 pair-blocks, 160 rows/block,
// one rendezvous/step, 4 MB/step broadcast, __syncthreads drains) with ONE
// change: rendezvous primitive. The 16-deep fetch_add RMW chain + tid0 spin
// is replaced by 16 plain dword stores into ONE 64B line per group (pipelined
// at the LLC write port, no ownership migration) + wave0 single-line ballot
// poll. Everything else byte-identical to the 1755us r4 kernel.
// Ledger: r1/r2 sc0-only XCD exchange BROKEN. r3 wide polling floods LLC
// (keep detect to ONE line). r4 broadcast BW+latency dominate. r5/r6 2-phase
// pipeline doubles rendezvous, loses 2x. r7 bundled changes (per-wave flags,
// 4-line detect, acc-liveness stretch) -> VGPR 248 + regression; change ONE
// thing at a time.

#define HH 512
#define TT 512

typedef _Float16 half8 __attribute__((ext_vector_type(8)));
typedef float f32x4 __attribute__((ext_vector_type(4)));

__device__ __forceinline__ float sigm(float x) { return 1.0f / (1.0f + __expf(-x)); }
__device__ __forceinline__ float tanh_(float x) { return 1.0f - 2.0f / (__expf(2.0f * x) + 1.0f); }
__device__ __forceinline__ unsigned short f16b(float x) {
    _Float16 h = (_Float16)x;
    return __builtin_bit_cast(unsigned short, h);
}

// ---------------- K1: W_eff gate rows -> Wbig (packed, f16) ----------------
__global__ __launch_bounds__(256) void k_weff(const float* __restrict__ Wih,
                                              const float* __restrict__ Whh,
                                              const float* __restrict__ Wlast,
                                              unsigned short* __restrict__ Wbig) {
    __shared__ float wih[16 * 512];
    const int tid = threadIdx.x;
    const int r0 = blockIdx.x * 16;
    for (int i = tid; i < (16 * 512) / 4; i += 256) {
        ((float4*)wih)[i] = ((const float4*)(Wih + (size_t)r0 * 512))[i];
    }
    __syncthreads();
    float acc0[16], acc1[16];
#pragma unroll
    for (int rr = 0; rr < 16; ++rr) { acc0[rr] = 0.f; acc1[rr] = 0.f; }
    const int k0 = tid * 2;
    for (int j = 0; j < 512; ++j) {
        const float2 wl = *(const float2*)(Wlast + (size_t)j * 512 + k0);
#pragma unroll
        for (int rr = 0; rr < 16; ++rr) {
            const float a = wih[rr * 512 + j];
            acc0[rr] += a * wl.x;
            acc1[rr] += a * wl.y;
        }
    }
#pragma unroll
    for (int rr = 0; rr < 16; ++rr) {
        const int gr = r0 + rr;
        const int q = gr >> 9, j = gr & 511;
        const int dst = 80 * (j >> 4) + q * 16 + (j & 15);
        const float v0 = acc0[rr] + Whh[(size_t)gr * 512 + k0];
        const float v1 = acc1[rr] + Whh[(size_t)gr * 512 + k0 + 1];
        Wbig[(size_t)dst * 512 + k0] = f16b(v0);
        Wbig[(size_t)dst * 512 + k0 + 1] = f16b(v1);
    }
}

// ---------------- K2: pack W0big, y-rows, biases, hbuf init, flags ------
__global__ __launch_bounds__(256) void k_pack(const float* __restrict__ z,
                                              const float* __restrict__ Wih,
                                              const float* __restrict__ Whh,
                                              const float* __restrict__ bih,
                                              const float* __restrict__ bhh,
                                              const float* __restrict__ Wlast,
                                              const float* __restrict__ blast,
                                              unsigned short* __restrict__ Wbig,
                                              unsigned short* __restrict__ W0big,
                                              float* __restrict__ biasEff,
                                              float* __restrict__ bias0,
                                              unsigned short* __restrict__ hbuf,
                                              unsigned int* __restrict__ flags) {
    const int nthr = gridDim.x * blockDim.x;
    const int gtid = blockIdx.x * blockDim.x + threadIdx.x;
    for (int e = gtid; e < 2560 * 512; e += nthr) {
        const int r = e >> 9, k = e & 511;
        const int s = r / 80, rem = r - s * 80;
        const int tau = rem >> 4, jj = rem & 15;
        const int j = s * 16 + jj;
        if (tau == 4) {
            const unsigned short v = f16b(Wlast[(size_t)j * 512 + k]);
            Wbig[e] = v;
            W0big[e] = v;
        } else {
            const int gr = tau * 512 + j;
            W0big[e] = f16b(Wih[(size_t)gr * 512 + k] + Whh[(size_t)gr * 512 + k]);
        }
    }
    for (int r = gtid; r < 2560; r += nthr) {
        const int s = r / 80, rem = r - s * 80;
        const int tau = rem >> 4, jj = rem & 15;
        const int j = s * 16 + jj;
        if (tau == 4) {
            bias0[r] = blast[j];
            biasEff[r] = blast[j];
        } else {
            const int gr = tau * 512 + j;
            const float base = bih[gr] + bhh[gr];
            float dot = 0.f;
            for (int k = 0; k < 512; ++k) dot += Wih[(size_t)gr * 512 + k] * blast[k];
            bias0[r] = base;
            biasEff[r] = base + dot;
        }
    }
    // hbuf: [g][parity][32 batch][512]; seed parity 0 with z
    for (int e = gtid; e < 256 * 512; e += nthr) {
        const int b = e >> 9, k = e & 511;
        const int g = b >> 5, bl = b & 31;
        hbuf[((size_t)(g * 2) * 32 + bl) * 512 + k] = f16b(z[e]);
    }
    // flags: 8 groups x 64 dwords (16 used = one 64B line per group)
    for (int e = gtid; e < 512; e += nthr) flags[e] = 0u;
}

// ---------------- K3: persistent recurrence ----------------
// 128 blocks = 8 groups (blockIdx&7) x 16 pairs (blockIdx>>3). A pair-block
// owns slices {2p, 2p+1} = 160 packed rows (128 gate rows + 32 y rows).
// Waves: w0: slice A x {i,f,g}; w1: slice A x {o,y}; w2: slice B x {i,f,g};
//        w3: slice B x {o,y}; each wave covers both 16-batch M-tiles.
__global__ __launch_bounds__(256, 1) void k_lstm(const unsigned short* __restrict__ Wbig,
                                                 const unsigned short* __restrict__ W0big,
                                                 const float* __restrict__ biasEff,
                                                 const float* __restrict__ bias0,
                                                 unsigned short* __restrict__ hbuf,
                                                 unsigned int* __restrict__ flags,
                                                 const float* __restrict__ z,
                                                 float* __restrict__ out) {
    const int g = blockIdx.x & 7;
    const int pair = blockIdx.x >> 3;
    const int tid = threadIdx.x;
    const int wave = tid >> 6;
    const int lane = tid & 63;
    const int l15 = lane & 15;
    const int q4 = lane >> 4;

    __shared__ unsigned short hstage[32 * 520];  // padded rows: stride 520 halves
    __shared__ float gatesL[2 * 32 * 68];        // [sl][b][i(16) f g o], stride 68
    __shared__ float cL[2 * 32 * 18];            // [sl][b][16 cells], stride 18

    const int sl = wave >> 1;            // which slice of the pair this wave serves
    const int slice = 2 * pair + sl;     // global slice id 0..31
    const int ntile0 = (wave & 1) ? 3 : 0;
    const int ntcount = (wave & 1) ? 2 : 3;

    unsigned short* hb0 = hbuf + (size_t)(g * 2) * 32 * 512;
    unsigned short* hb1 = hb0 + 32 * 512;
    unsigned int* fgrp = flags + g * 64;  // one 64B line per group (16 dwords used)

    // c init from z (fp32 exact) — both slices of the pair
    for (int idx = tid; idx < 1024; idx += 256) {
        const int s2 = idx >> 9;  // 0..1
        const int b = (idx >> 4) & 31, jj = idx & 15;
        cL[(s2 * 32 + b) * 18 + jj] =
            z[(size_t)(g * 32 + b) * 512 + 16 * (2 * pair + s2) + jj];
    }

    // persistent B-fragments (fp16 weights), start with W0
    half8 bfrag[3][16];
#pragma unroll
    for (int tt = 0; tt < 3; ++tt) {
        if (tt < ntcount) {
            const int row = 80 * slice + (ntile0 + tt) * 16 + l15;
#pragma unroll
            for (int kk = 0; kk < 16; ++kk) {
                bfrag[tt][kk] = *(const half8*)(W0big + (size_t)row * 512 + kk * 32 + q4 * 8);
            }
        }
    }
    float bias0v[3], biasEv[3];
#pragma unroll
    for (int tt = 0; tt < 3; ++tt) {
        if (tt < ntcount) {
            const int r = 80 * slice + (ntile0 + tt) * 16 + l15;
            bias0v[tt] = bias0[r];
            biasEv[tt] = biasEff[r];
        } else {
            bias0v[tt] = 0.f;
            biasEv[tt] = 0.f;
        }
    }

    for (int t = 0; t <= 512; ++t) {
        // ---- stage h(t): coherent LLC loads (sc0 sc1), pipelined, one wait ----
        // NOTE: outputs MUST be early-clobber (=&v): loads write dest regs while
        // later loads in the same asm block still need their address pairs.
        {
            const unsigned short* src = (t & 1) ? hb1 : hb0;
            const char* p = (const char*)src + tid * 16;
            half8 st[8];
            asm volatile(
                "global_load_dwordx4 %0, %8, off sc0 sc1\n\t"
                "global_load_dwordx4 %1, %9, off sc0 sc1\n\t"
                "global_load_dwordx4 %2, %10, off sc0 sc1\n\t"
                "global_load_dwordx4 %3, %11, off sc0 sc1\n\t"
                "global_load_dwordx4 %4, %12, off sc0 sc1\n\t"
                "global_load_dwordx4 %5, %13, off sc0 sc1\n\t"
                "global_load_dwordx4 %6, %14, off sc0 sc1\n\t"
                "global_load_dwordx4 %7, %15, off sc0 sc1\n\t"
                "s_waitcnt vmcnt(0)"
                : "=&v"(st[0]), "=&v"(st[1]), "=&v"(st[2]), "=&v"(st[3]),
                  "=&v"(st[4]), "=&v"(st[5]), "=&v"(st[6]), "=&v"(st[7])
                : "v"(p), "v"(p + 4096), "v"(p + 8192), "v"(p + 12288),
                  "v"(p + 16384), "v"(p + 20480), "v"(p + 24576), "v"(p + 28672)
                : "memory");
#pragma unroll
            for (int i = 0; i < 8; ++i) {
                const int ci = i * 256 + tid;  // 16B chunk index, 0..2047
                const int row = ci >> 6, col = ci & 63;
                *(half8*)(hstage + row * 520 + col * 8) = st[i];
            }
        }
        __syncthreads();

        // ---- MFMA: [gates | y] = h @ Wbig_pair^T + bias, both M-tiles ----
        f32x4 acc[3][2];
#pragma unroll
        for (int tt = 0; tt < 3; ++tt) {
            const float bv = (t == 0) ? bias0v[tt] : biasEv[tt];
            acc[tt][0] = (f32x4){bv, bv, bv, bv};
            acc[tt][1] = (f32x4){bv, bv, bv, bv};
        }
#pragma unroll
        for (int kk = 0; kk < 16; ++kk) {
            const half8 a0 = *(const half8*)(hstage + (l15)*520 + kk * 32 + q4 * 8);
            const half8 a1 = *(const half8*)(hstage + (16 + l15) * 520 + kk * 32 + q4 * 8);
#pragma unroll
            for (int tt = 0; tt < 3; ++tt) {
                if (tt < ntcount) {
                    acc[tt][0] = __builtin_amdgcn_mfma_f32_16x16x32_f16(a0, bfrag[tt][kk], acc[tt][0], 0, 0, 0);
                    acc[tt][1] = __builtin_amdgcn_mfma_f32_16x16x32_f16(a1, bfrag[tt][kk], acc[tt][1], 0, 0, 0);
                }
            }
        }

        // ---- y_{t-1} output (waves 1/3 hold the y tile in acc[1]) ----
        if ((wave & 1) && t >= 1) {
            const int n = 16 * slice + l15;
#pragma unroll
            for (int mt = 0; mt < 2; ++mt) {
#pragma unroll
                for (int r = 0; r < 4; ++r) {
                    const int m = mt * 16 + q4 * 4 + r;
                    const size_t off = (size_t)(g * 32 + m) * (TT * HH) + (size_t)(t - 1) * HH + n;
                    out[off] = acc[1][mt][r];
                }
            }
        }
        if (t == 512) break;

        // ---- gate tiles -> LDS ----
        {
            const int nst = (wave & 1) ? 1 : 3;
#pragma unroll
            for (int tt = 0; tt < 3; ++tt) {
                if (tt < nst) {
                    const int col = (ntile0 + tt) * 16 + l15;
#pragma unroll
                    for (int mt = 0; mt < 2; ++mt) {
#pragma unroll
                        for (int r = 0; r < 4; ++r) {
                            const int m = mt * 16 + q4 * 4 + r;
                            gatesL[(sl * 32 + m) * 68 + col] = acc[tt][mt][r];
                        }
                    }
                }
            }
        }
        __syncthreads();

        // ---- cell update: 4 cells/thread (2 slices x 2); publish h(t+1) ----
        {
            const int b = tid >> 3, jp = tid & 7;
            const int j0 = jp * 2;
            unsigned short* dst = (t & 1) ? hb0 : hb1;  // parity (t+1)&1
#pragma unroll
            for (int s2 = 0; s2 < 2; ++s2) {
                const float* gb = gatesL + (s2 * 32 + b) * 68;
                const float2 iv = *(const float2*)(gb + j0);
                const float2 fvv = *(const float2*)(gb + 16 + j0);
                const float2 gv = *(const float2*)(gb + 32 + j0);
                const float2 ov = *(const float2*)(gb + 48 + j0);
                float2 cv = *(const float2*)(cL + (s2 * 32 + b) * 18 + j0);
                const float c0 = sigm(fvv.x) * cv.x + sigm(iv.x) * tanh_(gv.x);
                const float c1 = sigm(fvv.y) * cv.y + sigm(iv.y) * tanh_(gv.y);
                const float h0 = sigm(ov.x) * tanh_(c0);
                const float h1 = sigm(ov.y) * tanh_(c1);
                cv.x = c0;
                cv.y = c1;
                *(float2*)(cL + (s2 * 32 + b) * 18 + j0) = cv;
                const unsigned int packed =
                    (unsigned int)f16b(h0) | ((unsigned int)f16b(h1) << 16);
                __hip_atomic_store(
                    (unsigned int*)(dst + b * 512 + 16 * (2 * pair + s2) + j0), packed,
                    __ATOMIC_RELAXED, __HIP_MEMORY_SCOPE_AGENT);
            }
        }

        // after step 0, swap persistent weights W0 -> W_eff (overlaps barrier)
        if (t == 0) {
#pragma unroll
            for (int tt = 0; tt < 3; ++tt) {
                if (tt < ntcount) {
                    const int row = 80 * slice + (ntile0 + tt) * 16 + l15;
#pragma unroll
                    for (int kk = 0; kk < 16; ++kk) {
                        bfrag[tt][kk] = *(const half8*)(Wbig + (size_t)row * 512 + kk * 32 + q4 * 8);
                    }
                }
            }
        }

        // ---- group barrier: single-line flag stores + single-line ballot ----
        // __syncthreads drains every thread's h(+y) stores (vmcnt ack at LLC)
        // before tid0 arrives, so the flag store is ordered after ALL of this
        // block's h data. 16 plain dword stores into one 64B line pipeline at
        // the LLC write port (no RMW ownership chain). wave0 polls that ONE
        // line (lanes replicate via lane&15) + __ballot; bounded guard.
        __syncthreads();
        if (tid == 0) {
            unsigned int* fp = fgrp + pair;
            const unsigned int fv = (unsigned int)t + 1u;
            asm volatile("global_store_dword %0, %1, off sc0 sc1" ::"v"(fp), "v"(fv)
                         : "memory");
        }
        if (wave == 0) {
            const unsigned int* fp = fgrp + (lane & 15);
            const unsigned int tgt = (unsigned int)t + 1u;
            unsigned int pv;
            int gd = 0;
            do {
                asm volatile("global_load_dword %0, %1, off sc0 sc1\n\ts_waitcnt vmcnt(0)"
                             : "=v"(pv)
                             : "v"(fp)
                             : "memory");
            } while (__ballot(pv >= tgt) != ~0ull && ++gd < 65536);
        }
        __syncthreads();
    }
}

// ---------------- launch ----------------
extern "C" void kernel_launch(void* const* d_in, const int* in_sizes, int n_in,
                              void* d_out, int out_size, void* d_ws, size_t ws_size,
                              hipStream_t stream) {
    const float* z = (const float*)d_in[0];
    const float* Wih = (const float*)d_in[1];
    const float* Whh = (const float*)d_in[2];
    const float* bih = (const float*)d_in[3];
    const float* bhh = (const float*)d_in[4];
    const float* Wlast = (const float*)d_in[5];
    const float* blast = (const float*)d_in[6];
    float* out = (float*)d_out;

    char* ws = (char*)d_ws;
    unsigned short* Wbig = (unsigned short*)(ws);                // 2,621,440 B
    unsigned short* W0big = (unsigned short*)(ws + 2621440);     // 2,621,440 B
    float* biasEff = (float*)(ws + 5242880);                     // 10,240 B
    float* bias0 = (float*)(ws + 5253120);                       // 10,240 B
    unsigned short* hbuf = (unsigned short*)(ws + 5263360);      // 524,288 B
    unsigned int* flags = (unsigned int*)(ws + 5787648);         // 2,048 B

    k_weff<<<128, 256, 0, stream>>>(Wih, Whh, Wlast, Wbig);
    k_pack<<<512, 256, 0, stream>>>(z, Wih, Whh, bih, bhh, Wlast, blast, Wbig, W0big, biasEff,
                                    bias0, hbuf, flags);
    k_lstm<<<128, 256, 0, stream>>>(Wbig, W0big, biasEff, bias0, hbuf, flags, z, out);
}

// Round 9
// 2139.401 us; speedup vs baseline: 1.9991x; 1.0300x over previous
//
#include <hip/hip_runtime.h>

// VaeRNNDecoder: 512-step LSTM with output feedback, B=256, H=512.
// Folded recurrence: gates_t = h_t @ W_eff^T + b_eff,  W_eff = W_ih@W_last + W_hh.
// ROUND 9: r4 structure VERBATIM (8 groups x 16 pair-blocks, 160 rows/block,
// fetch_add + tid0-spin rendezvous — proven best) with ONE change: h(t+1) is
// published via no-return global_atomic_swap instead of an sc0sc1 store.
// Rationale: WRITE_SIZE shows ~134MB of h traffic written through to HBM;
// the pre-publish __syncthreads' vmcnt(0) likely waits on that HBM ack
// (~900-1800cy) every step. Atomics execute at the LLC atomic unit: line
// stays LLC-resident, ack is LLC-side, visibility to sc0sc1 readers is the
// same coherence point as the baseline-proven protocol.
// Ledger: r1/r2 sc0-only XCD exchange BROKEN. r3 wide polling floods LLC.
// r4=1755us best. r5/r6 2-phase pipeline doubles rendezvous, loses 2x.
// r7 bundled changes regress (VGPR 248). r8 flag-line rendezvous 1877us:
// rendezvous primitive is NOT the lever (LLC atomics are pipelined).

#define HH 512
#define TT 512

typedef _Float16 half8 __attribute__((ext_vector_type(8)));
typedef float f32x4 __attribute__((ext_vector_type(4)));

__device__ __forceinline__ float sigm(float x) { return 1.0f / (1.0f + __expf(-x)); }
__device__ __forceinline__ float tanh_(float x) { return 1.0f - 2.0f / (__expf(2.0f * x) + 1.0f); }
__device__ __forceinline__ unsigned short f16b(float x) {
    _Float16 h = (_Float16)x;
    return __builtin_bit_cast(unsigned short, h);
}

// ---------------- K1: W_eff gate rows -> Wbig (packed, f16) ----------------
__global__ __launch_bounds__(256) void k_weff(const float* __restrict__ Wih,
                                              const float* __restrict__ Whh,
                                              const float* __restrict__ Wlast,
                                              unsigned short* __restrict__ Wbig) {
    __shared__ float wih[16 * 512];
    const int tid = threadIdx.x;
    const int r0 = blockIdx.x * 16;
    for (int i = tid; i < (16 * 512) / 4; i += 256) {
        ((float4*)wih)[i] = ((const float4*)(Wih + (size_t)r0 * 512))[i];
    }
    __syncthreads();
    float acc0[16], acc1[16];
#pragma unroll
    for (int rr = 0; rr < 16; ++rr) { acc0[rr] = 0.f; acc1[rr] = 0.f; }
    const int k0 = tid * 2;
    for (int j = 0; j < 512; ++j) {
        const float2 wl = *(const float2*)(Wlast + (size_t)j * 512 + k0);
#pragma unroll
        for (int rr = 0; rr < 16; ++rr) {
            const float a = wih[rr * 512 + j];
            acc0[rr] += a * wl.x;
            acc1[rr] += a * wl.y;
        }
    }
#pragma unroll
    for (int rr = 0; rr < 16; ++rr) {
        const int gr = r0 + rr;
        const int q = gr >> 9, j = gr & 511;
        const int dst = 80 * (j >> 4) + q * 16 + (j & 15);
        const float v0 = acc0[rr] + Whh[(size_t)gr * 512 + k0];
        const float v1 = acc1[rr] + Whh[(size_t)gr * 512 + k0 + 1];
        Wbig[(size_t)dst * 512 + k0] = f16b(v0);
        Wbig[(size_t)dst * 512 + k0 + 1] = f16b(v1);
    }
}

// ---------------- K2: pack W0big, y-rows, biases, hbuf init, counters ------
__global__ __launch_bounds__(256) void k_pack(const float* __restrict__ z,
                                              const float* __restrict__ Wih,
                                              const float* __restrict__ Whh,
                                              const float* __restrict__ bih,
                                              const float* __restrict__ bhh,
                                              const float* __restrict__ Wlast,
                                              const float* __restrict__ blast,
                                              unsigned short* __restrict__ Wbig,
                                              unsigned short* __restrict__ W0big,
                                              float* __restrict__ biasEff,
                                              float* __restrict__ bias0,
                                              unsigned short* __restrict__ hbuf,
                                              unsigned int* __restrict__ counters) {
    const int nthr = gridDim.x * blockDim.x;
    const int gtid = blockIdx.x * blockDim.x + threadIdx.x;
    for (int e = gtid; e < 2560 * 512; e += nthr) {
        const int r = e >> 9, k = e & 511;
        const int s = r / 80, rem = r - s * 80;
        const int tau = rem >> 4, jj = rem & 15;
        const int j = s * 16 + jj;
        if (tau == 4) {
            const unsigned short v = f16b(Wlast[(size_t)j * 512 + k]);
            Wbig[e] = v;
            W0big[e] = v;
        } else {
            const int gr = tau * 512 + j;
            W0big[e] = f16b(Wih[(size_t)gr * 512 + k] + Whh[(size_t)gr * 512 + k]);
        }
    }
    for (int r = gtid; r < 2560; r += nthr) {
        const int s = r / 80, rem = r - s * 80;
        const int tau = rem >> 4, jj = rem & 15;
        const int j = s * 16 + jj;
        if (tau == 4) {
            bias0[r] = blast[j];
            biasEff[r] = blast[j];
        } else {
            const int gr = tau * 512 + j;
            const float base = bih[gr] + bhh[gr];
            float dot = 0.f;
            for (int k = 0; k < 512; ++k) dot += Wih[(size_t)gr * 512 + k] * blast[k];
            bias0[r] = base;
            biasEff[r] = base + dot;
        }
    }
    // hbuf: [g][parity][32 batch][512]; seed parity 0 with z
    for (int e = gtid; e < 256 * 512; e += nthr) {
        const int b = e >> 9, k = e & 511;
        const int g = b >> 5, bl = b & 31;
        hbuf[((size_t)(g * 2) * 32 + bl) * 512 + k] = f16b(z[e]);
    }
    for (int e = gtid; e < 512; e += nthr) counters[e] = 0u;
}

// ---------------- K3: persistent recurrence ----------------
// 128 blocks = 8 groups (blockIdx&7) x 16 pairs (blockIdx>>3). A pair-block
// owns slices {2p, 2p+1} = 160 packed rows (128 gate rows + 32 y rows).
// Waves: w0: slice A x {i,f,g}; w1: slice A x {o,y}; w2: slice B x {i,f,g};
//        w3: slice B x {o,y}; each wave covers both 16-batch M-tiles.
__global__ __launch_bounds__(256, 1) void k_lstm(const unsigned short* __restrict__ Wbig,
                                                 const unsigned short* __restrict__ W0big,
                                                 const float* __restrict__ biasEff,
                                                 const float* __restrict__ bias0,
                                                 unsigned short* __restrict__ hbuf,
                                                 unsigned int* __restrict__ counters,
                                                 const float* __restrict__ z,
                                                 float* __restrict__ out) {
    const int g = blockIdx.x & 7;
    const int pair = blockIdx.x >> 3;
    const int tid = threadIdx.x;
    const int wave = tid >> 6;
    const int lane = tid & 63;
    const int l15 = lane & 15;
    const int q4 = lane >> 4;

    __shared__ unsigned short hstage[32 * 520];  // padded rows: stride 520 halves
    __shared__ float gatesL[2 * 32 * 68];        // [sl][b][i(16) f g o], stride 68
    __shared__ float cL[2 * 32 * 18];            // [sl][b][16 cells], stride 18

    const int sl = wave >> 1;            // which slice of the pair this wave serves
    const int slice = 2 * pair + sl;     // global slice id 0..31
    const int ntile0 = (wave & 1) ? 3 : 0;
    const int ntcount = (wave & 1) ? 2 : 3;

    unsigned short* hb0 = hbuf + (size_t)(g * 2) * 32 * 512;
    unsigned short* hb1 = hb0 + 32 * 512;
    unsigned int* cnt = counters + g * 64;

    // c init from z (fp32 exact) — both slices of the pair
    for (int idx = tid; idx < 1024; idx += 256) {
        const int s2 = idx >> 9;  // 0..1
        const int b = (idx >> 4) & 31, jj = idx & 15;
        cL[(s2 * 32 + b) * 18 + jj] =
            z[(size_t)(g * 32 + b) * 512 + 16 * (2 * pair + s2) + jj];
    }

    // persistent B-fragments (fp16 weights), start with W0
    half8 bfrag[3][16];
#pragma unroll
    for (int tt = 0; tt < 3; ++tt) {
        if (tt < ntcount) {
            const int row = 80 * slice + (ntile0 + tt) * 16 + l15;
#pragma unroll
            for (int kk = 0; kk < 16; ++kk) {
                bfrag[tt][kk] = *(const half8*)(W0big + (size_t)row * 512 + kk * 32 + q4 * 8);
            }
        }
    }
    float bias0v[3], biasEv[3];
#pragma unroll
    for (int tt = 0; tt < 3; ++tt) {
        if (tt < ntcount) {
            const int r = 80 * slice + (ntile0 + tt) * 16 + l15;
            bias0v[tt] = bias0[r];
            biasEv[tt] = biasEff[r];
        } else {
            bias0v[tt] = 0.f;
            biasEv[tt] = 0.f;
        }
    }

    for (int t = 0; t <= 512; ++t) {
        // ---- stage h(t): coherent LLC loads (sc0 sc1), pipelined, one wait ----
        // NOTE: outputs MUST be early-clobber (=&v): loads write dest regs while
        // later loads in the same asm block still need their address pairs.
        {
            const unsigned short* src = (t & 1) ? hb1 : hb0;
            const char* p = (const char*)src + tid * 16;
            half8 st[8];
            asm volatile(
                "global_load_dwordx4 %0, %8, off sc0 sc1\n\t"
                "global_load_dwordx4 %1, %9, off sc0 sc1\n\t"
                "global_load_dwordx4 %2, %10, off sc0 sc1\n\t"
                "global_load_dwordx4 %3, %11, off sc0 sc1\n\t"
                "global_load_dwordx4 %4, %12, off sc0 sc1\n\t"
                "global_load_dwordx4 %5, %13, off sc0 sc1\n\t"
                "global_load_dwordx4 %6, %14, off sc0 sc1\n\t"
                "global_load_dwordx4 %7, %15, off sc0 sc1\n\t"
                "s_waitcnt vmcnt(0)"
                : "=&v"(st[0]), "=&v"(st[1]), "=&v"(st[2]), "=&v"(st[3]),
                  "=&v"(st[4]), "=&v"(st[5]), "=&v"(st[6]), "=&v"(st[7])
                : "v"(p), "v"(p + 4096), "v"(p + 8192), "v"(p + 12288),
                  "v"(p + 16384), "v"(p + 20480), "v"(p + 24576), "v"(p + 28672)
                : "memory");
#pragma unroll
            for (int i = 0; i < 8; ++i) {
                const int ci = i * 256 + tid;  // 16B chunk index, 0..2047
                const int row = ci >> 6, col = ci & 63;
                *(half8*)(hstage + row * 520 + col * 8) = st[i];
            }
        }
        __syncthreads();

        // ---- MFMA: [gates | y] = h @ Wbig_pair^T + bias, both M-tiles ----
        f32x4 acc[3][2];
#pragma unroll
        for (int tt = 0; tt < 3; ++tt) {
            const float bv = (t == 0) ? bias0v[tt] : biasEv[tt];
            acc[tt][0] = (f32x4){bv, bv, bv, bv};
            acc[tt][1] = (f32x4){bv, bv, bv, bv};
        }
#pragma unroll
        for (int kk = 0; kk < 16; ++kk) {
            const half8 a0 = *(const half8*)(hstage + (l15)*520 + kk * 32 + q4 * 8);
            const half8 a1 = *(const half8*)(hstage + (16 + l15) * 520 + kk * 32 + q4 * 8);
#pragma unroll
            for (int tt = 0; tt < 3; ++tt) {
                if (tt < ntcount) {
                    acc[tt][0] = __builtin_amdgcn_mfma_f32_16x16x32_f16(a0, bfrag[tt][kk], acc[tt][0], 0, 0, 0);
                    acc[tt][1] = __builtin_amdgcn_mfma_f32_16x16x32_f16(a1, bfrag[tt][kk], acc[tt][1], 0, 0, 0);
                }
            }
        }

        // ---- y_{t-1} output (waves 1/3 hold the y tile in acc[1]) ----
        if ((wave & 1) && t >= 1) {
            const int n = 16 * slice + l15;
#pragma unroll
            for (int mt = 0; mt < 2; ++mt) {
#pragma unroll
                for (int r = 0; r < 4; ++r) {
                    const int m = mt * 16 + q4 * 4 + r;
                    const size_t off = (size_t)(g * 32 + m) * (TT * HH) + (size_t)(t - 1) * HH + n;
                    out[off] = acc[1][mt][r];
                }
            }
        }
        if (t == 512) break;

        // ---- gate tiles -> LDS ----
        {
            const int nst = (wave & 1) ? 1 : 3;
#pragma unroll
            for (int tt = 0; tt < 3; ++tt) {
                if (tt < nst) {
                    const int col = (ntile0 + tt) * 16 + l15;
#pragma unroll
                    for (int mt = 0; mt < 2; ++mt) {
#pragma unroll
                        for (int r = 0; r < 4; ++r) {
                            const int m = mt * 16 + q4 * 4 + r;
                            gatesL[(sl * 32 + m) * 68 + col] = acc[tt][mt][r];
                        }
                    }
                }
            }
        }
        __syncthreads();

        // ---- cell update: 4 cells/thread (2 slices x 2); publish h(t+1) ----
        // h publish = no-return global_atomic_swap: executes at the LLC atomic
        // unit, line stays LLC-resident (no HBM write-through on the ack path),
        // visible to other XCDs' sc0sc1 loads at the same coherence point.
        {
            const int b = tid >> 3, jp = tid & 7;
            const int j0 = jp * 2;
            unsigned short* dst = (t & 1) ? hb0 : hb1;  // parity (t+1)&1
#pragma unroll
            for (int s2 = 0; s2 < 2; ++s2) {
                const float* gb = gatesL + (s2 * 32 + b) * 68;
                const float2 iv = *(const float2*)(gb + j0);
                const float2 fvv = *(const float2*)(gb + 16 + j0);
                const float2 gv = *(const float2*)(gb + 32 + j0);
                const float2 ov = *(const float2*)(gb + 48 + j0);
                float2 cv = *(const float2*)(cL + (s2 * 32 + b) * 18 + j0);
                const float c0 = sigm(fvv.x) * cv.x + sigm(iv.x) * tanh_(gv.x);
                const float c1 = sigm(fvv.y) * cv.y + sigm(iv.y) * tanh_(gv.y);
                const float h0 = sigm(ov.x) * tanh_(c0);
                const float h1 = sigm(ov.y) * tanh_(c1);
                cv.x = c0;
                cv.y = c1;
                *(float2*)(cL + (s2 * 32 + b) * 18 + j0) = cv;
                const unsigned int packed =
                    (unsigned int)f16b(h0) | ((unsigned int)f16b(h1) << 16);
                unsigned int* pp = (unsigned int*)(dst + b * 512 + 16 * (2 * pair + s2) + j0);
                (void)__hip_atomic_exchange(pp, packed, __ATOMIC_RELAXED,
                                            __HIP_MEMORY_SCOPE_AGENT);
            }
        }

        // after step 0, swap persistent weights W0 -> W_eff (overlaps barrier)
        if (t == 0) {
#pragma unroll
            for (int tt = 0; tt < 3; ++tt) {
                if (tt < ntcount) {
                    const int row = 80 * slice + (ntile0 + tt) * 16 + l15;
#pragma unroll
                    for (int kk = 0; kk < 16; ++kk) {
                        bfrag[tt][kk] = *(const half8*)(Wbig + (size_t)row * 512 + kk * 32 + q4 * 8);
                    }
                }
            }
        }

        // ---- group barrier: relaxed agent counter, narrow tid0 spin ----
        // __syncthreads drains every thread's h atomics (vmcnt ack at the LLC
        // atomic unit) before tid0 arrives, so readers polling the counter and
        // then loading with sc0 sc1 observe the new h values.
        __syncthreads();
        if (tid == 0) {
            __hip_atomic_fetch_add(cnt, 1u, __ATOMIC_RELAXED, __HIP_MEMORY_SCOPE_AGENT);
            const unsigned int target = 16u * (unsigned)(t + 1);
            int guard = 0;
            while (__hip_atomic_load(cnt, __ATOMIC_RELAXED, __HIP_MEMORY_SCOPE_AGENT) < target &&
                   ++guard < 65536) {
            }
        }
        __syncthreads();
    }
}

// ---------------- launch ----------------
extern "C" void kernel_launch(void* const* d_in, const int* in_sizes, int n_in,
                              void* d_out, int out_size, void* d_ws, size_t ws_size,
                              hipStream_t stream) {
    const float* z = (const float*)d_in[0];
    const float* Wih = (const float*)d_in[1];
    const float* Whh = (const float*)d_in[2];
    const float* bih = (const float*)d_in[3];
    const float* bhh = (const float*)d_in[4];
    const float* Wlast = (const float*)d_in[5];
    const float* blast = (const float*)d_in[6];
    float* out = (float*)d_out;

    char* ws = (char*)d_ws;
    unsigned short* Wbig = (unsigned short*)(ws);                // 2,621,440 B
    unsigned short* W0big = (unsigned short*)(ws + 2621440);     // 2,621,440 B
    float* biasEff = (float*)(ws + 5242880);                     // 10,240 B
    float* bias0 = (float*)(ws + 5253120);                       // 10,240 B
    unsigned short* hbuf = (unsigned short*)(ws + 5263360);      // 524,288 B
    unsigned int* counters = (unsigned int*)(ws + 5787648);      // 2,048 B

    k_weff<<<128, 256, 0, stream>>>(Wih, Whh, Wlast, Wbig);
    k_pack<<<512, 256, 0, stream>>>(z, Wih, Whh, bih, bhh, Wlast, blast, Wbig, W0big, biasEff,
                                    bias0, hbuf, counters);
    k_lstm<<<128, 256, 0, stream>>>(Wbig, W0big, biasEff, bias0, hbuf, counters, z, out);
}